// Round 6
// baseline (98.556 us; speedup 1.0000x reference)
//
#include <hip/hip_runtime.h>

// EMA y[t] = a*x[t] + (1-a)*y[t-1], y_prev init = x[0] (so y[0]==x[0]).
// R4/R5: pure-register segmented scan, NO LDS, NO barriers.
//   - lane owns 16 contiguous elements (wave covers contiguous 4KB span)
//   - local zero-init scan l[j] in regs
//   - carry via truncated affine composition over prior lanes' segment ends:
//       y[t0-1] ~= l(i-1) + 0.7^16 l(i-2) + 0.7^32 l(i-3)   (err ~ 0.7^48)
//   - y[j] = l[j] + 0.7^(j+1) * carry  (1 FMA/elem, constant coefficients)
//   - lanes 0..2: divergent 32-elem global warm-up (L1-hot); row start exact.
// All register indexing is compile-time constant (R2's spill lesson).
// R5 fix: scalar fmaf per component (no vector fmaf overload on device).

#define AL 0.3f
#define BE 0.7f
#define BLOCK 256
#define RPT 16                    // elements per lane
#define F16 0.0033232930569601f   // 0.7^16
#define F32 1.10450644586e-05f    // 0.7^32

typedef float floatx4 __attribute__((ext_vector_type(4)));

__global__ __launch_bounds__(BLOCK) void ema_kernel(
    const float* __restrict__ x, float* __restrict__ y,
    int T, int tilesPerRow) {
  const int tid     = threadIdx.x;
  const int lane    = tid & 63;
  const int tile_t0 = (blockIdx.x % tilesPerRow) * (BLOCK * RPT);
  const int t0      = tile_t0 + (tid >> 6) * (64 * RPT) + lane * RPT;
  const size_t rowoff = (size_t)(blockIdx.x / tilesPerRow) * (size_t)T;
  const float* xrow = x + rowoff;
  float*       yrow = y + rowoff;

  // ---- load own 16 elements (wave64 spans contiguous 4KB) ----
  const float* px = xrow + t0;
  floatx4 a0 = *(const floatx4*)(px);
  floatx4 a1 = *(const floatx4*)(px + 4);
  floatx4 a2 = *(const floatx4*)(px + 8);
  floatx4 a3 = *(const floatx4*)(px + 12);
  const float x0 = a0[0];

  // ---- local zero-init scan, overwrite in place (static indices only) ----
  float c = 0.f;
#define STEP(v, i) c = fmaf(AL, (v)[i], BE * c); (v)[i] = c;
  STEP(a0,0) STEP(a0,1) STEP(a0,2) STEP(a0,3)
  STEP(a1,0) STEP(a1,1) STEP(a1,2) STEP(a1,3)
  STEP(a2,0) STEP(a2,1) STEP(a2,2) STEP(a2,3)
  STEP(a3,0) STEP(a3,1) STEP(a3,2) STEP(a3,3)
#undef STEP
  const float lend = c;

  // ---- carry composition (shuffles before divergence: all lanes active) ----
  const float s1 = __shfl_up(lend, 1, 64);
  const float s2 = __shfl_up(lend, 2, 64);
  const float s3 = __shfl_up(lend, 3, 64);

  float cin;
  if (lane >= 3) {
    cin = fmaf(F16, s2, fmaf(F32, s3, s1));
  } else if (t0 == 0) {
    cin = x0;                       // y[-1] := x[0] reproduces y[0]=x[0] exactly
  } else if (t0 >= 32) {
    // zero-init 32-step warm-up; init error 0.7^32 ~ 1.1e-5
    const float* ph = xrow + t0 - 32;
    float cc = 0.f;
#pragma unroll 8
    for (int k = 0; k < 32; ++k) cc = fmaf(AL, ph[k], BE * cc);
    cin = cc;
  } else {
    // row-start lanes 1..2 (t0 = 16 or 32): exact from y[0]=x[0]
    float cc = xrow[0];
    for (int t = 1; t < t0; ++t) cc = fmaf(AL, xrow[t], BE * cc);
    cin = cc;
  }

  // ---- combine: y[j] = l[j] + 0.7^(j+1) * cin (static indices) ----
  const float P[16] = {
    0.7f, 0.49f, 0.343f, 0.2401f,
    0.16807f, 0.117649f, 0.0823543f, 0.05764801f,
    0.040353607f, 0.0282475249f, 0.019773267f, 0.013841287f,
    0.009688901f, 0.0067822307f, 0.0047475615f, 0.0033232931f };
#define CMB(v, i, j) (v)[i] = fmaf(cin, P[j], (v)[i]);
  CMB(a0,0,0)  CMB(a0,1,1)  CMB(a0,2,2)  CMB(a0,3,3)
  CMB(a1,0,4)  CMB(a1,1,5)  CMB(a1,2,6)  CMB(a1,3,7)
  CMB(a2,0,8)  CMB(a2,1,9)  CMB(a2,2,10) CMB(a2,3,11)
  CMB(a3,0,12) CMB(a3,1,13) CMB(a3,2,14) CMB(a3,3,15)
#undef CMB

  // ---- NT store own 16 (output never re-read; keep L3 for input) ----
  float* py = yrow + t0;
  __builtin_nontemporal_store(a0, (floatx4*)(py));
  __builtin_nontemporal_store(a1, (floatx4*)(py + 4));
  __builtin_nontemporal_store(a2, (floatx4*)(py + 8));
  __builtin_nontemporal_store(a3, (floatx4*)(py + 12));
}

extern "C" void kernel_launch(void* const* d_in, const int* in_sizes, int n_in,
                              void* d_out, int out_size, void* d_ws, size_t ws_size,
                              hipStream_t stream) {
  const float* x = (const float*)d_in[0];
  float* y = (float*)d_out;

  const int T = 65536;                          // per problem spec
  const int B = in_sizes[0] / T;                // 512
  const int tilesPerRow = T / (BLOCK * RPT);    // 16
  const int grid = B * tilesPerRow;             // 8192 blocks

  ema_kernel<<<grid, BLOCK, 0, stream>>>(x, y, T, tilesPerRow);
}

// Round 7
// 61.017 us; speedup vs baseline: 1.6152x; 1.6152x over previous
//
#include <hip/hip_runtime.h>

// EMA y[t] = a*x[t] + (1-a)*y[t-1], y_prev init = x[0] (so y[0]==x[0]).
// R6: pure-register segmented scan, RPT=4 so per-wave load AND store are
// exactly contiguous (64 lanes x float4 = 1KB full cachelines) -> NT stores
// carry no partial-line write amplification (R5's 1.9x WRITE bug).
//   - lane owns 4 contiguous elems; local zero-init scan in regs
//   - carry = attenuated Kogge-Stone over 8 predecessor lanes (32-elem halo,
//     trunc err 0.7^32 ~ 1.1e-5 << 2e-2 threshold):
//       s += 0.7^4 * shfl_up(s,1); s += 0.7^8 * shfl_up(s,2);
//       s += 0.7^16 * shfl_up(s,4);  cin = shfl_up(s,1)
//   - lanes 0..7: divergent 32-elem global warm-up (window ~2 cachelines,
//     L2/L3-hot); row start clamps to exact y[0]=x[0] init.
// All register indexing compile-time constant (R2 spill lesson).

#define AL  0.3f
#define BE  0.7f
#define Q4  0.2401f          // 0.7^4
#define Q8  0.05764801f      // 0.7^8
#define Q16 0.0033232931f    // 0.7^16
#define BLOCK 256
#define RPT 4                // elements per lane
#define WCH (64 * RPT)       // 256 elems per wave
#define BCH (BLOCK * RPT)    // 1024 elems per block

typedef float floatx4 __attribute__((ext_vector_type(4)));

__global__ __launch_bounds__(BLOCK) void ema_kernel(
    const float* __restrict__ x, float* __restrict__ y,
    int T, int tilesPerRow) {
  const int tid  = threadIdx.x;
  const int lane = tid & 63;
  const int t0   = (blockIdx.x % tilesPerRow) * BCH + (tid >> 6) * WCH + lane * RPT;
  const size_t rowoff = (size_t)(blockIdx.x / tilesPerRow) * (size_t)T;
  const float* xrow = x + rowoff;
  float*       yrow = y + rowoff;

  // ---- load own 4 elements (wave = contiguous aligned 1KB) ----
  floatx4 a = *(const floatx4*)(xrow + t0);
  const float x0 = a[0];

  // ---- local zero-init scan (static indices) ----
  float c = 0.f;
  c = fmaf(AL, a[0], BE * c); a[0] = c;
  c = fmaf(AL, a[1], BE * c); a[1] = c;
  c = fmaf(AL, a[2], BE * c); a[2] = c;
  c = fmaf(AL, a[3], BE * c); a[3] = c;

  // ---- attenuated Kogge-Stone over 8 predecessor lanes ----
  // (all shuffles unconditional: every lane active)
  float s = c;
  s = fmaf(Q4,  __shfl_up(s, 1, 64), s);
  s = fmaf(Q8,  __shfl_up(s, 2, 64), s);
  s = fmaf(Q16, __shfl_up(s, 4, 64), s);   // s_i = sum_{k=0..7} 0.7^{4k} l_{i-k}
  const float sprev = __shfl_up(s, 1, 64); // = approx y[t0-1] for lane>=8

  float cin;
  if (lane >= 8) {
    cin = sprev;
  } else if (t0 == 0) {
    cin = x0;                    // y[-1] := x[0] reproduces y[0]=x[0] exactly
  } else if (t0 >= 32) {
    // zero-init 32-step warm-up; init error 0.7^32 ~ 1.1e-5
    const float* ph = xrow + t0 - 32;
    float cc = 0.f;
#pragma unroll 8
    for (int k = 0; k < 32; ++k) cc = fmaf(AL, ph[k], BE * cc);
    cin = cc;
  } else {
    // row-start lanes 1..7 (t0 = 4..28): exact from y[0]=x[0]
    float cc = xrow[0];
    for (int t = 1; t < t0; ++t) cc = fmaf(AL, xrow[t], BE * cc);
    cin = cc;
  }

  // ---- combine: y[j] = l[j] + 0.7^(j+1) * cin ----
  a[0] = fmaf(cin, 0.7f,    a[0]);
  a[1] = fmaf(cin, 0.49f,   a[1]);
  a[2] = fmaf(cin, 0.343f,  a[2]);
  a[3] = fmaf(cin, 0.2401f, a[3]);

  // ---- NT store (full contiguous lines per wave; keep L3 for input) ----
  __builtin_nontemporal_store(a, (floatx4*)(yrow + t0));
}

extern "C" void kernel_launch(void* const* d_in, const int* in_sizes, int n_in,
                              void* d_out, int out_size, void* d_ws, size_t ws_size,
                              hipStream_t stream) {
  const float* x = (const float*)d_in[0];
  float* y = (float*)d_out;

  const int T = 65536;                    // per problem spec
  const int B = in_sizes[0] / T;          // 512
  const int tilesPerRow = T / BCH;        // 64
  const int grid = B * tilesPerRow;       // 32768 blocks

  ema_kernel<<<grid, BLOCK, 0, stream>>>(x, y, T, tilesPerRow);
}

// Round 8
// 45.823 us; speedup vs baseline: 2.1508x; 1.3316x over previous
//
#include <hip/hip_runtime.h>

// EMA y[t] = a*x[t] + (1-a)*y[t-1], y_prev init = x[0] (so y[0]==x[0]).
// R7: register-only segmented scan with wave-internal seed chaining.
// Key: 0.7^256 == 0 in fp32, so a 256-elem wave-chunk's exit state depends
// only on that chunk. Each wave owns SEG=NI*256 contiguous elems:
//   chunk scan: lane holds 4 elems -> zero-init local scan l[j], then masked
//   attenuated Kogge-Stone (offsets 1,2,4; coeffs 0.7^4,0.7^8,0.7^16) gives
//   s_i = sum_{k=0..7} 0.7^{4k} L_{i-k} (32-elem window, trunc 0.7^32~1.1e-5)
//   cin_i = shfl_up(s,1)|0 + 0.7^{4i} * seed ;  y[j] = l[j] + 0.7^{j+1} cin
//   seed_next = shfl(s,63)   (exact: 0.7^256 underflows)
// First-chunk seed: one PARALLEL halo-chunk scan (replaces R6's 32-step
// serial warm-up chain that cost ~300cy per 256 outputs). Row start: seed=x0
// reproduces y[0]=x[0] exactly.
// NOTE: __shfl_up clamps at the wave edge (returns own value) -> must zero
// the contributions for lanes < delta (cndmask), else s_0..s_2 corrupt.

#define AL  0.3f
#define BE  0.7f
#define Q4  0.2401f
#define Q8  0.05764801f
#define Q16 0.0033232931f
#define LOG2_07_X4 -2.0582926913190332f   // 4*log2(0.7)
#define BLOCK 256
#define NI  16                 // chunks per wave segment
#define WCH 256                // elems per wave-chunk (64 lanes x 4)
#define SEG (NI * WCH)         // 4096 elems per wave

typedef float floatx4 __attribute__((ext_vector_type(4)));

__device__ __forceinline__ float masked_ks(float lend, int lane) {
  // attenuated Kogge-Stone over up to 8 predecessor lanes, clamp-safe
  float s = lend;
  float t = __shfl_up(s, 1, 64); if (lane < 1) t = 0.f;
  s = fmaf(Q4, t, s);
  t = __shfl_up(s, 2, 64);      if (lane < 2) t = 0.f;
  s = fmaf(Q8, t, s);
  t = __shfl_up(s, 4, 64);      if (lane < 4) t = 0.f;
  s = fmaf(Q16, t, s);
  return s;
}

__global__ __launch_bounds__(BLOCK, 8) void ema_kernel(
    const float* __restrict__ x, float* __restrict__ y, int T) {
  const int tid  = threadIdx.x;
  const int lane = tid & 63;
  const int gw   = blockIdx.x * (BLOCK / 64) + (tid >> 6);
  const int row  = gw >> 4;                 // 16 segments per row
  const int seg  = (gw & 15) * SEG;         // segment start within row
  const size_t rowoff = (size_t)row * (size_t)T;
  const float* xrow = x + rowoff;
  float*       yrow = y + rowoff;
  const int lb = lane * 4;                  // lane offset within a chunk

  const float pw = exp2f(LOG2_07_X4 * (float)lane);   // 0.7^(4*lane)

  // ---- chunk-0 load + seed (wave-uniform branch) ----
  floatx4 a = *(const floatx4*)(xrow + seg + lb);
  float seed;
  if (seg == 0) {
    seed = __shfl(a[0], 0, 64);             // x[0]: exact row init
  } else {
    // parallel halo-chunk scan over [seg-256, seg)
    const floatx4 h = *(const floatx4*)(xrow + seg - WCH + lb);
    float c = 0.f;
    c = fmaf(AL, h[0], BE * c);
    c = fmaf(AL, h[1], BE * c);
    c = fmaf(AL, h[2], BE * c);
    c = fmaf(AL, h[3], BE * c);
    seed = __shfl(masked_ks(c, lane), 63, 64);
  }

  // ---- main loop: NI chunks, prefetch distance 1 ----
#pragma unroll
  for (int ci = 0; ci < NI; ++ci) {
    floatx4 nx;
    if (ci + 1 < NI)
      nx = *(const floatx4*)(xrow + seg + (ci + 1) * WCH + lb);

    float c = 0.f;
    c = fmaf(AL, a[0], BE * c); a[0] = c;
    c = fmaf(AL, a[1], BE * c); a[1] = c;
    c = fmaf(AL, a[2], BE * c); a[2] = c;
    c = fmaf(AL, a[3], BE * c); a[3] = c;

    const float s = masked_ks(c, lane);
    float sp = __shfl_up(s, 1, 64); if (lane == 0) sp = 0.f;
    const float cin = fmaf(pw, seed, sp);

    a[0] = fmaf(cin, 0.7f,    a[0]);
    a[1] = fmaf(cin, 0.49f,   a[1]);
    a[2] = fmaf(cin, 0.343f,  a[2]);
    a[3] = fmaf(cin, 0.2401f, a[3]);

    __builtin_nontemporal_store(a, (floatx4*)(yrow + seg + ci * WCH + lb));

    seed = __shfl(s, 63, 64);               // next chunk's seed (no serial chain)
    a = nx;
  }
}

extern "C" void kernel_launch(void* const* d_in, const int* in_sizes, int n_in,
                              void* d_out, int out_size, void* d_ws, size_t ws_size,
                              hipStream_t stream) {
  const float* x = (const float*)d_in[0];
  float* y = (float*)d_out;

  const int T = 65536;                          // per problem spec
  const int B = in_sizes[0] / T;                // 512
  const int wavesTotal = B * (T / SEG);         // 8192
  const int grid = wavesTotal / (BLOCK / 64);   // 2048 blocks = 8/CU exactly

  ema_kernel<<<grid, BLOCK, 0, stream>>>(x, y, T);
}

// Round 9
// 45.289 us; speedup vs baseline: 2.1762x; 1.0118x over previous
//
#include <hip/hip_runtime.h>

// EMA y[t] = a*x[t] + (1-a)*y[t-1], y_prev init = x[0] (so y[0]==x[0]).
// R8 = R7 math (register-only segmented scan, wave-chunk seed chaining via
// attenuated Kogge-Stone; 0.7^256==0 in fp32 so chunk exit state is local)
// with two scheduling fixes:
//   - SEG 4096->2048 (NI=8): 4096 blocks = 16/CU backfill queue (R7's exact
//     8/CU grid had no slack -> 56% occupancy tail)
//   - prefetch depth 2: two loads in flight per wave vs HBM ~900cy latency
// Per chunk: lane owns 4 elems; zero-init local scan; masked KS (offsets
// 1,2,4 coeffs 0.7^4,0.7^8,0.7^16) => 32-elem window, trunc err 1.1e-5;
// cin = shfl_up(s,1)|0 + 0.7^(4*lane)*seed; y[j]=l[j]+0.7^(j+1)*cin;
// seed' = shfl(s,63). First chunk seeds from one parallel halo-chunk scan
// (in-block predecessor wave's last chunk -> L1/L2-hot). Row start: seed=x[0].
// __shfl_up clamps at wave edge -> explicit zeroing for lanes < delta.

#define AL  0.3f
#define BE  0.7f
#define Q4  0.2401f
#define Q8  0.05764801f
#define Q16 0.0033232931f
#define LOG2_07_X4 -2.0582926913190332f   // 4*log2(0.7)
#define BLOCK 256
#define NI  8                  // chunks per wave segment
#define WCH 256                // elems per wave-chunk (64 lanes x 4)
#define SEG (NI * WCH)         // 2048 elems per wave

typedef float floatx4 __attribute__((ext_vector_type(4)));

__device__ __forceinline__ float masked_ks(float lend, int lane) {
  float s = lend;
  float t = __shfl_up(s, 1, 64); if (lane < 1) t = 0.f;
  s = fmaf(Q4, t, s);
  t = __shfl_up(s, 2, 64);      if (lane < 2) t = 0.f;
  s = fmaf(Q8, t, s);
  t = __shfl_up(s, 4, 64);      if (lane < 4) t = 0.f;
  s = fmaf(Q16, t, s);          // s_i = sum_{k=0..7} 0.7^{4k} L_{i-k}
  return s;
}

__global__ __launch_bounds__(BLOCK, 8) void ema_kernel(
    const float* __restrict__ x, float* __restrict__ y, int T) {
  const int tid  = threadIdx.x;
  const int lane = tid & 63;
  const int gw   = blockIdx.x * (BLOCK / 64) + (tid >> 6);
  const int segsPerRow = 65536 / SEG;       // 32
  const int row  = gw >> 5;
  const int seg  = (gw & (segsPerRow - 1)) * SEG;
  const size_t rowoff = (size_t)row * (size_t)T;
  const float* xrow = x + rowoff;
  float*       yrow = y + rowoff;
  const int lb = lane * 4;
  const float* ps = xrow + seg;

  // ---- issue first three loads up front (depth-2 pipeline + halo) ----
  floatx4 cur = *(const floatx4*)(ps + lb);              // chunk 0
  floatx4 n1  = *(const floatx4*)(ps + WCH + lb);        // chunk 1

  const float pw = exp2f(LOG2_07_X4 * (float)lane);      // 0.7^(4*lane)

  float seed;
  if (seg == 0) {
    seed = __shfl(cur[0], 0, 64);            // x[0]: exact row init
  } else {
    const floatx4 h = *(const floatx4*)(ps - WCH + lb);  // halo chunk
    float c = 0.f;
    c = fmaf(AL, h[0], BE * c);
    c = fmaf(AL, h[1], BE * c);
    c = fmaf(AL, h[2], BE * c);
    c = fmaf(AL, h[3], BE * c);
    seed = __shfl(masked_ks(c, lane), 63, 64);
  }

  // ---- main loop: NI chunks, prefetch distance 2, full unroll ----
#pragma unroll
  for (int ci = 0; ci < NI; ++ci) {
    floatx4 n2;
    if (ci + 2 < NI)
      n2 = *(const floatx4*)(ps + (ci + 2) * WCH + lb);

    float c = 0.f;
    c = fmaf(AL, cur[0], BE * c); cur[0] = c;
    c = fmaf(AL, cur[1], BE * c); cur[1] = c;
    c = fmaf(AL, cur[2], BE * c); cur[2] = c;
    c = fmaf(AL, cur[3], BE * c); cur[3] = c;

    const float s = masked_ks(c, lane);
    float sp = __shfl_up(s, 1, 64); if (lane == 0) sp = 0.f;
    const float cin = fmaf(pw, seed, sp);

    cur[0] = fmaf(cin, 0.7f,    cur[0]);
    cur[1] = fmaf(cin, 0.49f,   cur[1]);
    cur[2] = fmaf(cin, 0.343f,  cur[2]);
    cur[3] = fmaf(cin, 0.2401f, cur[3]);

    __builtin_nontemporal_store(cur, (floatx4*)(yrow + seg + ci * WCH + lb));

    seed = __shfl(s, 63, 64);               // next chunk's seed
    cur = n1;
    n1 = n2;
  }
}

extern "C" void kernel_launch(void* const* d_in, const int* in_sizes, int n_in,
                              void* d_out, int out_size, void* d_ws, size_t ws_size,
                              hipStream_t stream) {
  const float* x = (const float*)d_in[0];
  float* y = (float*)d_out;

  const int T = 65536;                          // per problem spec
  const int B = in_sizes[0] / T;                // 512
  const int wavesTotal = B * (T / SEG);         // 16384
  const int grid = wavesTotal / (BLOCK / 64);   // 4096 blocks = 16/CU

  ema_kernel<<<grid, BLOCK, 0, stream>>>(x, y, T);
}

// Round 10
// 44.888 us; speedup vs baseline: 2.1956x; 1.0089x over previous
//
#include <hip/hip_runtime.h>

// EMA y[t] = a*x[t] + (1-a)*y[t-1], y_prev init = x[0] (so y[0]==x[0]).
// R9 = R8 math (register segmented scan; 0.7^256==0 in fp32 -> chunk exit
// state is chunk-local; masked attenuated Kogge-Stone gives per-chunk carry;
// seed chains across chunks via one shfl) with the load pipeline FORCED:
// all 8 chunk loads + halo issued up front into NAMED registers (R8's
// VGPR=24 proved the compiler collapsed the "prefetch" to depth ~1; a wave
// then has 1 outstanding load vs ~900cy HBM latency -> latency-bound 45us
// plateau). 9 loads in flight/wave x 32 waves/CU covers latency fully.
// ~50 VGPR total, <=64 so 8 waves/SIMD retained.

#define AL  0.3f
#define BE  0.7f
#define Q4  0.2401f
#define Q8  0.05764801f
#define Q16 0.0033232931f
#define LOG2_07_X4 -2.0582926913190332f   // 4*log2(0.7)
#define BLOCK 256
#define NI  8                  // chunks per wave segment
#define WCH 256                // elems per wave-chunk (64 lanes x 4)
#define SEG (NI * WCH)         // 2048 elems per wave

typedef float floatx4 __attribute__((ext_vector_type(4)));

__device__ __forceinline__ float masked_ks(float lend, int lane) {
  float s = lend;
  float t = __shfl_up(s, 1, 64); if (lane < 1) t = 0.f;
  s = fmaf(Q4, t, s);
  t = __shfl_up(s, 2, 64);      if (lane < 2) t = 0.f;
  s = fmaf(Q8, t, s);
  t = __shfl_up(s, 4, 64);      if (lane < 4) t = 0.f;
  s = fmaf(Q16, t, s);          // s_i = sum_{k=0..7} 0.7^{4k} L_{i-k}
  return s;
}

__global__ __launch_bounds__(BLOCK, 8) void ema_kernel(
    const float* __restrict__ x, float* __restrict__ y, int T) {
  const int tid  = threadIdx.x;
  const int lane = tid & 63;
  const int gw   = blockIdx.x * (BLOCK / 64) + (tid >> 6);
  const int segsPerRow = 65536 / SEG;       // 32
  const int row  = gw >> 5;
  const int seg  = (gw & (segsPerRow - 1)) * SEG;
  const size_t rowoff = (size_t)row * (size_t)T;
  const float* xrow = x + rowoff;
  float*       yrow = y + rowoff;
  const int lb = lane * 4;
  const float* ps = xrow + seg;

  // ---- issue ALL loads up front: 8 chunks into named regs (9KB in flight) ----
  floatx4 c0 = *(const floatx4*)(ps + 0 * WCH + lb);
  floatx4 c1 = *(const floatx4*)(ps + 1 * WCH + lb);
  floatx4 c2 = *(const floatx4*)(ps + 2 * WCH + lb);
  floatx4 c3 = *(const floatx4*)(ps + 3 * WCH + lb);
  floatx4 c4 = *(const floatx4*)(ps + 4 * WCH + lb);
  floatx4 c5 = *(const floatx4*)(ps + 5 * WCH + lb);
  floatx4 c6 = *(const floatx4*)(ps + 6 * WCH + lb);
  floatx4 c7 = *(const floatx4*)(ps + 7 * WCH + lb);

  const float pw = exp2f(LOG2_07_X4 * (float)lane);      // 0.7^(4*lane)

  float seed;
  if (seg == 0) {
    seed = __shfl(c0[0], 0, 64);             // x[0]: exact row init
  } else {
    const floatx4 h = *(const floatx4*)(ps - WCH + lb);  // halo chunk
    float hc = 0.f;
    hc = fmaf(AL, h[0], BE * hc);
    hc = fmaf(AL, h[1], BE * hc);
    hc = fmaf(AL, h[2], BE * hc);
    hc = fmaf(AL, h[3], BE * hc);
    seed = __shfl(masked_ks(hc, lane), 63, 64);
  }

  // ---- drain chunks in order (static names; stores overlap later waits) ----
#define CHUNK(i)                                                          \
  {                                                                       \
    float t = 0.f;                                                        \
    t = fmaf(AL, c##i[0], BE * t); c##i[0] = t;                           \
    t = fmaf(AL, c##i[1], BE * t); c##i[1] = t;                           \
    t = fmaf(AL, c##i[2], BE * t); c##i[2] = t;                           \
    t = fmaf(AL, c##i[3], BE * t); c##i[3] = t;                           \
    const float s = masked_ks(t, lane);                                   \
    float sp = __shfl_up(s, 1, 64); if (lane == 0) sp = 0.f;              \
    const float cin = fmaf(pw, seed, sp);                                 \
    c##i[0] = fmaf(cin, 0.7f,    c##i[0]);                                \
    c##i[1] = fmaf(cin, 0.49f,   c##i[1]);                                \
    c##i[2] = fmaf(cin, 0.343f,  c##i[2]);                                \
    c##i[3] = fmaf(cin, 0.2401f, c##i[3]);                                \
    __builtin_nontemporal_store(c##i, (floatx4*)(yrow + seg + (i) * WCH + lb)); \
    seed = __shfl(s, 63, 64);                                             \
  }
  CHUNK(0) CHUNK(1) CHUNK(2) CHUNK(3)
  CHUNK(4) CHUNK(5) CHUNK(6) CHUNK(7)
#undef CHUNK
}

extern "C" void kernel_launch(void* const* d_in, const int* in_sizes, int n_in,
                              void* d_out, int out_size, void* d_ws, size_t ws_size,
                              hipStream_t stream) {
  const float* x = (const float*)d_in[0];
  float* y = (float*)d_out;

  const int T = 65536;                          // per problem spec
  const int B = in_sizes[0] / T;                // 512
  const int wavesTotal = B * (T / SEG);         // 16384
  const int grid = wavesTotal / (BLOCK / 64);   // 4096 blocks = 16/CU

  ema_kernel<<<grid, BLOCK, 0, stream>>>(x, y, T);
}